// Round 16
// baseline (175.243 us; speedup 1.0000x reference)
//
#include <hip/hip_runtime.h>
#include <hip/hip_bf16.h>

#define N_NODES 50000
#define IN_CH 128
#define HID 128
#define OUT_CH 64
#define N_EDGES 800000
#define N_TOT_EDGES (N_EDGES + N_NODES)         // + self loops
#define ET_PAD (N_TOT_EDGES + 3 * N_NODES)      // worst-case pad-to-4 per node
#define MPAD 50048                              // 782 * 64 (gemm row-block pad)
#define NBX (MPAD / 16)                         // 3128 cvtX blocks

typedef float float4v __attribute__((ext_vector_type(4)));
typedef unsigned uint4v __attribute__((ext_vector_type(4)));
typedef __attribute__((ext_vector_type(8))) short bf16x8;
typedef __attribute__((ext_vector_type(4))) float f32x4;

__device__ __forceinline__ unsigned bf16_rne(float f) {
    unsigned u = __float_as_uint(f);
    return (u + 0x7fffu + ((u >> 16) & 1u)) >> 16;
}
__device__ __forceinline__ unsigned pack2(float a, float b) {
    return bf16_rne(a) | (bf16_rne(b) << 16);
}

// ---------------- CSR build ----------------

__global__ void k_init_cnt(int* cnt, int n) {
    int i = blockIdx.x * 256 + threadIdx.x;
    if (i < n) cnt[i] = 1;   // self-loop reserves slot 0 of each segment
}

// count + RANK capture: rank[i] = old count (1..deg) -> fill is atomic-free.
__global__ void k_count(const int* __restrict__ dst_row, int* __restrict__ cnt,
                        unsigned short* __restrict__ rank, int e) {
    int i = blockIdx.x * 256 + threadIdx.x;
    if (i < e) {
        int d = __builtin_nontemporal_load(&dst_row[i]);   // read-once stream
        rank[i] = (unsigned short)atomicAdd(&cnt[d], 1);
    }
}

// inclusive scan of PADDED counts -> off[i+1]; per-block sums to bsum.
__global__ void k_scan1(const int* __restrict__ cnt, int* __restrict__ off,
                        int* __restrict__ bsum, int n) {
    __shared__ int s[256];
    int t = threadIdx.x;
    int i = blockIdx.x * 256 + t;
    int v = (i < n) ? ((cnt[i] + 3) & ~3) : 0;   // pad segments to 4
    s[t] = v;
    __syncthreads();
    for (int d = 1; d < 256; d <<= 1) {
        int x = (t >= d) ? s[t - d] : 0;
        __syncthreads();
        s[t] += x;
        __syncthreads();
    }
    if (i < n) off[i + 1] = s[t];
    if (t == 255) bsum[blockIdx.x] = s[255];
}

__global__ void k_scan2(int* __restrict__ bsum, int nb) {  // single block, nb <= 256
    __shared__ int s[256];
    int t = threadIdx.x;
    int v = (t < nb) ? bsum[t] : 0;
    s[t] = v;
    __syncthreads();
    for (int d = 1; d < 256; d <<= 1) {
        int x = (t >= d) ? s[t - d] : 0;
        __syncthreads();
        s[t] += x;
        __syncthreads();
    }
    if (t < nb) bsum[t] = s[t] - v;  // exclusive prefix
}

__global__ void k_scan3(int* __restrict__ off, const int* __restrict__ bsum, int n) {
    int i = blockIdx.x * 256 + threadIdx.x;
    if (i < n) off[i + 1] += bsum[blockIdx.x];
    if (i == 0) off[0] = 0;
}

// atomic-free fill: edge i -> csr[off[dst] + rank[i]]; self-loop v -> slot 0.
__global__ void k_fill2(const int* __restrict__ ei, const int* __restrict__ off,
                        const unsigned short* __restrict__ rank,
                        int* __restrict__ csr, int e, int n) {
    int i = blockIdx.x * 256 + threadIdx.x;
    if (i < e) {
        int src = __builtin_nontemporal_load(&ei[i]);
        int dst = __builtin_nontemporal_load(&ei[e + i]);
        csr[off[dst] + rank[i]] = src;
    } else if (i < e + n) {
        int v = i - e;
        csr[off[v]] = v;
    }
}

// ---------------- fused f32 -> bf16 tiled conversions for MFMA ----------------
// blocks [0, NBX): X -> Xb[row>>4][kg][row&15][8]
// blocks [NBX, NBX+8): W1 -> Wl1[kg][col][8]  (16*128 cols)
// blocks [NBX+8, NBX+12): W2 -> Wl2[kg][col][8]
__global__ __launch_bounds__(256) void k_cvtAll(
        const float* __restrict__ X, unsigned short* __restrict__ Xb,
        const float* __restrict__ W1, unsigned short* __restrict__ Wl1,
        const float* __restrict__ W2, unsigned short* __restrict__ Wl2, int M) {
    const int b = blockIdx.x;
    const int t = threadIdx.x;
    if (b < NBX) {
        const int kg = t >> 4, rl = t & 15;
        const int row = b * 16 + rl;
        float4 a = make_float4(0.f, 0.f, 0.f, 0.f), c = a;
        if (row < M) {
            a = *(const float4*)&X[(size_t)row * 128 + kg * 8];
            c = *(const float4*)&X[(size_t)row * 128 + kg * 8 + 4];
        }
        uint4 p;
        p.x = pack2(a.x, a.y); p.y = pack2(a.z, a.w);
        p.z = pack2(c.x, c.y); p.w = pack2(c.z, c.w);
        *(uint4*)&Xb[(size_t)b * 2048 + kg * 128 + rl * 8] = p;
        return;
    }
    const float* W; unsigned short* Wl; int N, bb;
    if (b < NBX + 8) { W = W1; Wl = Wl1; N = 128; bb = b - NBX; }
    else             { W = W2; Wl = Wl2; N = 64;  bb = b - NBX - 8; }
    const int tg = bb * 256 + t;
    if (tg >= 16 * N) return;
    const int kg = tg / N, col = tg & (N - 1);
    float v[8];
    #pragma unroll
    for (int j = 0; j < 8; ++j) v[j] = W[(size_t)(kg * 8 + j) * N + col];
    uint4 p;
    p.x = pack2(v[0], v[1]); p.y = pack2(v[2], v[3]);
    p.z = pack2(v[4], v[5]); p.w = pack2(v[6], v[7]);
    *(uint4*)&Wl[(size_t)tg * 8] = p;
}

// ---------------- MFMA GEMM (h = X @ W) + fused attention dots ----------------
// Block = 4 waves; wave = 16 rows x ALL N cols (attention dots atomic-free).
// C/D layout (guide-verified m89/m91): col = lane&15, row = (lane>>4)*4 + reg.
template<int N, bool BF16OUT>
__global__ __launch_bounds__(256) void gemm_mfma(
        const unsigned short* __restrict__ Xb, const unsigned short* __restrict__ Wlg,
        const float* __restrict__ asrc, const float* __restrict__ adst,
        void* __restrict__ HcV, float* __restrict__ als, float* __restrict__ ald,
        int M) {
    constexpr int NF = N / 16;
    __shared__ unsigned short Wl[16 * N * 8];
    const int t = threadIdx.x;
    for (int i = t; i < N * 16; i += 256)
        ((uint4*)Wl)[i] = ((const uint4*)Wlg)[i];
    __syncthreads();

    const int lane = t & 63, w = t >> 6;
    const int rb = blockIdx.x * 64 + w * 16;
    const int cl = lane & 15, g = lane >> 4;
    const unsigned short* __restrict__ Abase = Xb + (size_t)(rb >> 4) * 2048 + cl * 8;

    f32x4 acc[NF];
    #pragma unroll
    for (int n = 0; n < NF; ++n) acc[n] = (f32x4){0.f, 0.f, 0.f, 0.f};

    #pragma unroll
    for (int s = 0; s < 4; ++s) {
        bf16x8 af = *(const bf16x8*)(Abase + (s * 4 + g) * 128);
        #pragma unroll
        for (int n = 0; n < NF; ++n) {
            bf16x8 bf = *(const bf16x8*)(Wl + ((s * 4 + g) * N + n * 16 + cl) * 8);
            acc[n] = __builtin_amdgcn_mfma_f32_16x16x32_bf16(af, bf, acc[n], 0, 0, 0);
        }
    }

    float asv[NF], adv[NF];
    #pragma unroll
    for (int n = 0; n < NF; ++n) {
        asv[n] = asrc[n * 16 + cl];
        adv[n] = adst[n * 16 + cl];
    }

    #pragma unroll
    for (int r = 0; r < 4; ++r) {
        float ps = 0.f, pd = 0.f;
        #pragma unroll
        for (int n = 0; n < NF; ++n) {
            ps += acc[n][r] * asv[n];
            pd += acc[n][r] * adv[n];
        }
        #pragma unroll
        for (int mask = 1; mask < 16; mask <<= 1) {
            ps += __shfl_xor(ps, mask);
            pd += __shfl_xor(pd, mask);
        }
        const int row = rb + g * 4 + r;
        if (cl == 0 && row < M) { als[row] = ps; ald[row] = pd; }
    }

    #pragma unroll
    for (int r = 0; r < 4; ++r) {
        const int row = rb + g * 4 + r;
        if (row >= M) continue;
        if (BF16OUT) {
            unsigned short* Hb = (unsigned short*)HcV;
            #pragma unroll
            for (int n = 0; n < NF; ++n)
                Hb[(size_t)(n >> 1) * (size_t)M * 32 + (size_t)row * 32
                   + (n & 1) * 16 + cl] = (unsigned short)bf16_rne(acc[n][r]);
        } else {
            float* Hc = (float*)HcV;
            #pragma unroll
            for (int n = 0; n < NF; ++n)
                Hc[(size_t)n * (size_t)M * 16 + (size_t)row * 16 + cl] = acc[n][r];
        }
    }
}

// ---------------- edge weights: packed u32 = (src<<16) | bf16(exp(leaky(e))) ----
// Also writes the <=3 pad slots per node to 0 (src=0, w=+0.0) -> no memset
// dispatch needed (r15: the 4MB hipMemsetAsync went through the runtime's
// slow fill kernel, ~13us per replay).
__global__ __launch_bounds__(256) void k_edgew(
        const float* __restrict__ als, const float* __restrict__ ald,
        const int* __restrict__ off, const int* __restrict__ cnt,
        const int* __restrict__ csr,
        unsigned* __restrict__ ew, float* __restrict__ invden, int n) {
    const int fl = threadIdx.x & 15;
    const int v = blockIdx.x * 16 + (threadIdx.x >> 4);
    if (v >= n) return;
    const int start = off[v], end = start + cnt[v];
    const int pend = off[v + 1];
    const float aldv = ald[v];
    float s = 0.f;
    for (int j = start + fl; j < end; j += 16) {
        int src = __builtin_nontemporal_load(&csr[j]);
        float e = als[src] + aldv;
        e = e > 0.f ? e : 0.2f * e;
        unsigned r = bf16_rne(__expf(e));
        ew[j] = ((unsigned)src << 16) | r;
        s += __uint_as_float(r << 16);
    }
    for (int j = end + fl; j < pend; j += 16) ew[j] = 0;   // pad slots
    #pragma unroll
    for (int d = 1; d < 16; d <<= 1) s += __shfl_xor(s, d);
    if (fl == 0) invden[v] = 1.f / (s + 1e-16f);
}

// ---------------- layer-1 SpMM (bf16 H, 32-feature chunks, 4 passes) ------------
// Writes y1 DIRECTLY in the Xb-tiled bf16 layout gemm2 consumes; nt store.
__global__ __launch_bounds__(256) void k_spmm_bf16(
        const unsigned short* __restrict__ Hb, const unsigned* __restrict__ ew,
        const float* __restrict__ invden, const float* __restrict__ bias,
        const int* __restrict__ off, unsigned short* __restrict__ Xb2, int n) {
    const int chunk = blockIdx.x & 3;             // NCH = 128/32 = 4
    const int v = (blockIdx.x >> 2) * 64 + (threadIdx.x >> 2);
    if (v >= n) return;
    const int q = threadIdx.x & 3;                // 8-feat group 0..3
    const int start = off[v], end = off[v + 1];   // padded: multiple of 4, >= 4
    const unsigned short* __restrict__ Hch = Hb + (size_t)chunk * (size_t)n * 32 + q * 8;

    float a0[8] = {}, a1[8] = {}, a2[8] = {}, a3[8] = {};

    #define GATB(E, A)                                                   \
        {                                                                \
            float w_ = __uint_as_float((E) << 16);                       \
            uint4 h_ = *(const uint4*)&Hch[(size_t)((E) >> 16) * 32];    \
            A[0] += w_ * __uint_as_float(h_.x << 16);                    \
            A[1] += w_ * __uint_as_float(h_.x & 0xffff0000u);            \
            A[2] += w_ * __uint_as_float(h_.y << 16);                    \
            A[3] += w_ * __uint_as_float(h_.y & 0xffff0000u);            \
            A[4] += w_ * __uint_as_float(h_.z << 16);                    \
            A[5] += w_ * __uint_as_float(h_.z & 0xffff0000u);            \
            A[6] += w_ * __uint_as_float(h_.w << 16);                    \
            A[7] += w_ * __uint_as_float(h_.w & 0xffff0000u);            \
        }
    #define GATB4(Q) GATB((Q).x, a0) GATB((Q).y, a1) GATB((Q).z, a2) GATB((Q).w, a3)

    int j = start;
    for (; j + 4 < end; j += 8) {
        uint4 eA = *(const uint4*)&ew[j];
        uint4 eB = *(const uint4*)&ew[j + 4];
        GATB4(eA)
        GATB4(eB)
    }
    if (j < end) {
        uint4 eA = *(const uint4*)&ew[j];
        GATB4(eA)
    }
    #undef GATB4
    #undef GATB

    const float inv = invden[v];
    const float* __restrict__ bp = bias + chunk * 32 + q * 8;
    float s[8];
    #pragma unroll
    for (int i = 0; i < 8; ++i)
        s[i] = fmaxf((a0[i] + a1[i] + a2[i] + a3[i]) * inv + bp[i], 0.f);

    const int kg = chunk * 4 + q;
    uint4v p;
    p[0] = pack2(s[0], s[1]); p[1] = pack2(s[2], s[3]);
    p[2] = pack2(s[4], s[5]); p[3] = pack2(s[6], s[7]);
    __builtin_nontemporal_store(p,
        (uint4v*)&Xb2[(size_t)(v >> 4) * 2048 + kg * 128 + (v & 15) * 8]);
}

// ---------------- layer-2 SpMM (f32 H, 16-feature chunks) ----------------
__global__ __launch_bounds__(256) void k_spmm_f32(
        const float* __restrict__ Hc, const unsigned* __restrict__ ew,
        const float* __restrict__ invden, const float* __restrict__ bias,
        const int* __restrict__ off, float* __restrict__ out, int n) {
    const int chunk = blockIdx.x & 3;             // NCH = 64/16 = 4
    const int v = (blockIdx.x >> 2) * 64 + (threadIdx.x >> 2);
    if (v >= n) return;
    const int q = threadIdx.x & 3;                // feature quad 0..3
    const int start = off[v], end = off[v + 1];
    const float* __restrict__ Hch = Hc + (size_t)chunk * (size_t)n * 16 + q * 4;

    float4 a0 = make_float4(0.f, 0.f, 0.f, 0.f);
    float4 a1 = make_float4(0.f, 0.f, 0.f, 0.f);
    float4 a2 = make_float4(0.f, 0.f, 0.f, 0.f);
    float4 a3 = make_float4(0.f, 0.f, 0.f, 0.f);

    #define GAT(E, A)                                                  \
        {                                                              \
            float w_ = __uint_as_float((E) << 16);                     \
            float4 h_ = *(const float4*)&Hch[(size_t)((E) >> 16) * 16];\
            A.x += w_ * h_.x; A.y += w_ * h_.y;                        \
            A.z += w_ * h_.z; A.w += w_ * h_.w;                        \
        }
    #define GAT4(Q) GAT((Q).x, a0) GAT((Q).y, a1) GAT((Q).z, a2) GAT((Q).w, a3)

    int j = start;
    for (; j + 4 < end; j += 8) {
        uint4 eA = *(const uint4*)&ew[j];
        uint4 eB = *(const uint4*)&ew[j + 4];
        GAT4(eA)
        GAT4(eB)
    }
    if (j < end) {
        uint4 eA = *(const uint4*)&ew[j];
        GAT4(eA)
    }
    #undef GAT4
    #undef GAT

    const float inv = invden[v];
    const float4 b = *(const float4*)&bias[chunk * 16 + q * 4];
    float4v o;
    o[0] = (a0.x + a1.x + a2.x + a3.x) * inv + b.x;
    o[1] = (a0.y + a1.y + a2.y + a3.y) * inv + b.y;
    o[2] = (a0.z + a1.z + a2.z + a3.z) * inv + b.z;
    o[3] = (a0.w + a1.w + a2.w + a3.w) * inv + b.w;
    __builtin_nontemporal_store(o, (float4v*)&out[(size_t)v * OUT_CH + chunk * 16 + q * 4]);
}

// ---------------- launch ----------------

extern "C" void kernel_launch(void* const* d_in, const int* in_sizes, int n_in,
                              void* d_out, int out_size, void* d_ws, size_t ws_size,
                              hipStream_t stream) {
    const float* x     = (const float*)d_in[0];
    const int*   ei    = (const int*)d_in[1];
    const float* W1    = (const float*)d_in[2];
    const float* as1   = (const float*)d_in[3];
    const float* ad1   = (const float*)d_in[4];
    const float* b1    = (const float*)d_in[5];
    const float* W2    = (const float*)d_in[6];
    const float* as2   = (const float*)d_in[7];
    const float* ad2   = (const float*)d_in[8];
    const float* b2    = (const float*)d_in[9];
    float* out = (float*)d_out;

    const int Nn = N_NODES, E = N_EDGES, ET = N_TOT_EDGES;

    // workspace carve-up (256B aligned)
    char* ws = (char*)d_ws;
    size_t o = 0;
    auto carve = [&](size_t bytes) { char* p = ws + o; o = (o + bytes + 255) & ~(size_t)255; return p; };
    int*            off  = (int*)carve((Nn + 1) * sizeof(int));
    int*            cnt  = (int*)carve(Nn * sizeof(int));
    int*            bsum = (int*)carve(256 * sizeof(int));
    unsigned short* rank = (unsigned short*)carve((size_t)E * sizeof(unsigned short));
    int*            csr  = (int*)carve((size_t)ET_PAD * sizeof(int));
    unsigned*       ew   = (unsigned*)carve((size_t)ET_PAD * sizeof(unsigned));
    unsigned short* h1b  = (unsigned short*)carve((size_t)Nn * HID * sizeof(unsigned short));
    float*          h2   = (float*)carve((size_t)Nn * OUT_CH * sizeof(float));
    unsigned short* Xb1  = (unsigned short*)carve((size_t)MPAD * 128 * sizeof(unsigned short));
    unsigned short* Xb2  = (unsigned short*)carve((size_t)MPAD * 128 * sizeof(unsigned short));
    unsigned short* Wl1  = (unsigned short*)carve(16 * 128 * 8 * sizeof(unsigned short));
    unsigned short* Wl2  = (unsigned short*)carve(16 * 64 * 8 * sizeof(unsigned short));
    float*          als  = (float*)carve(Nn * sizeof(float));
    float*          ald  = (float*)carve(Nn * sizeof(float));
    float*          invd = (float*)carve(Nn * sizeof(float));

    const int nbN   = (Nn + 255) / 256;
    const int nbE   = (E + 255) / 256;
    const int nbET  = (ET + 255) / 256;

    // CSR build: count captures ranks; fill is atomic-free; no ew memset
    k_init_cnt<<<nbN, 256, 0, stream>>>(cnt, Nn);
    k_count<<<nbE, 256, 0, stream>>>(ei + E, cnt, rank, E);
    k_scan1<<<nbN, 256, 0, stream>>>(cnt, off, bsum, Nn);
    k_scan2<<<1, 256, 0, stream>>>(bsum, nbN);
    k_scan3<<<nbN, 256, 0, stream>>>(off, bsum, Nn);
    k_fill2<<<nbET, 256, 0, stream>>>(ei, off, rank, csr, E, Nn);

    // fused bf16 conversions (X, W1, W2 in one dispatch)
    k_cvtAll<<<NBX + 12, 256, 0, stream>>>(x, Xb1, W1, Wl1, W2, Wl2, Nn);

    const int nbEW   = (Nn + 15) / 16;
    const int nbN64  = (Nn + 63) / 64;
    const int nbGEMM = MPAD / 64;   // 782

    // layer 1
    gemm_mfma<HID, true><<<nbGEMM, 256, 0, stream>>>(
        Xb1, Wl1, as1, ad1, h1b, als, ald, Nn);
    k_edgew<<<nbEW, 256, 0, stream>>>(als, ald, off, cnt, csr, ew, invd, Nn);
    k_spmm_bf16<<<nbN64 * 4, 256, 0, stream>>>(h1b, ew, invd, b1, off, Xb2, Nn);

    // layer 2
    gemm_mfma<OUT_CH, false><<<nbGEMM, 256, 0, stream>>>(
        Xb2, Wl2, as2, ad2, h2, als, ald, Nn);
    k_edgew<<<nbEW, 256, 0, stream>>>(als, ald, off, cnt, csr, ew, invd, Nn);
    k_spmm_f32<<<nbN64 * 4, 256, 0, stream>>>(h2, ew, invd, b2, off, out, Nn);
}

// Round 17
// 165.037 us; speedup vs baseline: 1.0618x; 1.0618x over previous
//
#include <hip/hip_runtime.h>
#include <hip/hip_bf16.h>

#define N_NODES 50000
#define IN_CH 128
#define HID 128
#define OUT_CH 64
#define N_EDGES 800000
#define N_TOT_EDGES (N_EDGES + N_NODES)         // + self loops
#define ET_PAD (N_TOT_EDGES + 3 * N_NODES)      // worst-case pad-to-4 per node
#define MPAD 50048                              // 782 * 64 (gemm row-block pad)
#define NBX (MPAD / 16)                         // 3128 cvtX blocks
#define NBN ((N_NODES + 255) / 256)             // 196

typedef float float4v __attribute__((ext_vector_type(4)));
typedef unsigned uint4v __attribute__((ext_vector_type(4)));
typedef __attribute__((ext_vector_type(8))) short bf16x8;
typedef __attribute__((ext_vector_type(4))) float f32x4;

__device__ __forceinline__ unsigned bf16_rne(float f) {
    unsigned u = __float_as_uint(f);
    return (u + 0x7fffu + ((u >> 16) & 1u)) >> 16;
}
__device__ __forceinline__ unsigned pack2(float a, float b) {
    return bf16_rne(a) | (bf16_rne(b) << 16);
}

// ---------------- CSR build ----------------

// count + RANK capture: rank[i] = old count (1..deg) -> fill is atomic-free.
__global__ void k_count(const int* __restrict__ dst_row, int* __restrict__ cnt,
                        unsigned short* __restrict__ rank, int e) {
    int i = blockIdx.x * 256 + threadIdx.x;
    if (i < e) {
        int d = __builtin_nontemporal_load(&dst_row[i]);   // read-once stream
        rank[i] = (unsigned short)atomicAdd(&cnt[d], 1);
    }
}

// inclusive scan of PADDED counts -> off[i+1]; per-block sums to bsum.
__global__ void k_scan1(const int* __restrict__ cnt, int* __restrict__ off,
                        int* __restrict__ bsum, int n) {
    __shared__ int s[256];
    int t = threadIdx.x;
    int i = blockIdx.x * 256 + t;
    int v = (i < n) ? ((cnt[i] + 3) & ~3) : 0;   // pad segments to 4
    s[t] = v;
    __syncthreads();
    for (int d = 1; d < 256; d <<= 1) {
        int x = (t >= d) ? s[t - d] : 0;
        __syncthreads();
        s[t] += x;
        __syncthreads();
    }
    if (i < n) off[i + 1] = s[t];
    if (t == 255) bsum[blockIdx.x] = s[255];
}

__global__ void k_scan2(int* __restrict__ bsum, int nb) {  // single block, nb <= 256
    __shared__ int s[256];
    int t = threadIdx.x;
    int v = (t < nb) ? bsum[t] : 0;
    s[t] = v;
    __syncthreads();
    for (int d = 1; d < 256; d <<= 1) {
        int x = (t >= d) ? s[t - d] : 0;
        __syncthreads();
        s[t] += x;
        __syncthreads();
    }
    if (t < nb) bsum[t] = s[t] - v;  // exclusive prefix
}

__global__ void k_scan3(int* __restrict__ off, const int* __restrict__ bsum, int n) {
    int i = blockIdx.x * 256 + threadIdx.x;
    if (i < n) off[i + 1] += bsum[blockIdx.x];
    if (i == 0) off[0] = 0;
}

// atomic-free fill: edge i -> csr[off[dst] + rank[i]]; self-loop v -> slot 0.
__global__ void k_fill2(const int* __restrict__ ei, const int* __restrict__ off,
                        const unsigned short* __restrict__ rank,
                        int* __restrict__ csr, int e, int n) {
    int i = blockIdx.x * 256 + threadIdx.x;
    if (i < e) {
        int src = __builtin_nontemporal_load(&ei[i]);
        int dst = __builtin_nontemporal_load(&ei[e + i]);
        csr[off[dst] + rank[i]] = src;
    } else if (i < e + n) {
        int v = i - e;
        csr[off[v]] = v;
    }
}

// ---------------- fused conversions + cnt init (one dispatch) ----------------
// blocks [0, NBX): X -> Xb[row>>4][kg][row&15][8]
// blocks [NBX, NBX+8): W1 -> Wl1[kg][col][8]
// blocks [NBX+8, NBX+12): W2 -> Wl2[kg][col][8]
// blocks [NBX+12, NBX+12+NBN): cnt[i] = 1 (self-loop reserves slot 0)
__global__ __launch_bounds__(256) void k_cvtAll(
        const float* __restrict__ X, unsigned short* __restrict__ Xb,
        const float* __restrict__ W1, unsigned short* __restrict__ Wl1,
        const float* __restrict__ W2, unsigned short* __restrict__ Wl2,
        int* __restrict__ cnt, int M) {
    const int b = blockIdx.x;
    const int t = threadIdx.x;
    if (b < NBX) {
        const int kg = t >> 4, rl = t & 15;
        const int row = b * 16 + rl;
        float4 a = make_float4(0.f, 0.f, 0.f, 0.f), c = a;
        if (row < M) {
            a = *(const float4*)&X[(size_t)row * 128 + kg * 8];
            c = *(const float4*)&X[(size_t)row * 128 + kg * 8 + 4];
        }
        uint4 p;
        p.x = pack2(a.x, a.y); p.y = pack2(a.z, a.w);
        p.z = pack2(c.x, c.y); p.w = pack2(c.z, c.w);
        *(uint4*)&Xb[(size_t)b * 2048 + kg * 128 + rl * 8] = p;
        return;
    }
    if (b >= NBX + 12) {
        int i = (b - NBX - 12) * 256 + t;
        if (i < M) cnt[i] = 1;
        return;
    }
    const float* W; unsigned short* Wl; int N, bb;
    if (b < NBX + 8) { W = W1; Wl = Wl1; N = 128; bb = b - NBX; }
    else             { W = W2; Wl = Wl2; N = 64;  bb = b - NBX - 8; }
    const int tg = bb * 256 + t;
    if (tg >= 16 * N) return;
    const int kg = tg / N, col = tg & (N - 1);
    float v[8];
    #pragma unroll
    for (int j = 0; j < 8; ++j) v[j] = W[(size_t)(kg * 8 + j) * N + col];
    uint4 p;
    p.x = pack2(v[0], v[1]); p.y = pack2(v[2], v[3]);
    p.z = pack2(v[4], v[5]); p.w = pack2(v[6], v[7]);
    *(uint4*)&Wl[(size_t)tg * 8] = p;
}

// ---------------- MFMA GEMM (h = X @ W) + fused attention dots ----------------
// Block = 4 waves; wave = 16 rows x ALL N cols (attention dots atomic-free).
// C/D layout (guide-verified m89/m91): col = lane&15, row = (lane>>4)*4 + reg.
// Both layers now emit bf16 H in 32-feature chunks (layer2: 2 chunks ->
// spmm does 2 passes instead of 4; every gathered 64B line fully used).
template<int N>
__global__ __launch_bounds__(256) void gemm_mfma(
        const unsigned short* __restrict__ Xb, const unsigned short* __restrict__ Wlg,
        const float* __restrict__ asrc, const float* __restrict__ adst,
        unsigned short* __restrict__ Hb, float* __restrict__ als, float* __restrict__ ald,
        int M) {
    constexpr int NF = N / 16;
    __shared__ unsigned short Wl[16 * N * 8];
    const int t = threadIdx.x;
    for (int i = t; i < N * 16; i += 256)
        ((uint4*)Wl)[i] = ((const uint4*)Wlg)[i];
    __syncthreads();

    const int lane = t & 63, w = t >> 6;
    const int rb = blockIdx.x * 64 + w * 16;
    const int cl = lane & 15, g = lane >> 4;
    const unsigned short* __restrict__ Abase = Xb + (size_t)(rb >> 4) * 2048 + cl * 8;

    f32x4 acc[NF];
    #pragma unroll
    for (int n = 0; n < NF; ++n) acc[n] = (f32x4){0.f, 0.f, 0.f, 0.f};

    #pragma unroll
    for (int s = 0; s < 4; ++s) {
        bf16x8 af = *(const bf16x8*)(Abase + (s * 4 + g) * 128);
        #pragma unroll
        for (int n = 0; n < NF; ++n) {
            bf16x8 bf = *(const bf16x8*)(Wl + ((s * 4 + g) * N + n * 16 + cl) * 8);
            acc[n] = __builtin_amdgcn_mfma_f32_16x16x32_bf16(af, bf, acc[n], 0, 0, 0);
        }
    }

    float asv[NF], adv[NF];
    #pragma unroll
    for (int n = 0; n < NF; ++n) {
        asv[n] = asrc[n * 16 + cl];
        adv[n] = adst[n * 16 + cl];
    }

    #pragma unroll
    for (int r = 0; r < 4; ++r) {
        float ps = 0.f, pd = 0.f;
        #pragma unroll
        for (int n = 0; n < NF; ++n) {
            ps += acc[n][r] * asv[n];
            pd += acc[n][r] * adv[n];
        }
        #pragma unroll
        for (int mask = 1; mask < 16; mask <<= 1) {
            ps += __shfl_xor(ps, mask);
            pd += __shfl_xor(pd, mask);
        }
        const int row = rb + g * 4 + r;
        if (cl == 0 && row < M) { als[row] = ps; ald[row] = pd; }
    }

    #pragma unroll
    for (int r = 0; r < 4; ++r) {
        const int row = rb + g * 4 + r;
        if (row >= M) continue;
        #pragma unroll
        for (int n = 0; n < NF; ++n)
            Hb[(size_t)(n >> 1) * (size_t)M * 32 + (size_t)row * 32
               + (n & 1) * 16 + cl] = (unsigned short)bf16_rne(acc[n][r]);
    }
}

// ---------------- edge weights: packed u32 = (src<<16) | bf16(exp(leaky(e))) ----
// Writes the <=3 pad slots per node to 0 (src=0, w=+0.0) -> no memset dispatch.
__global__ __launch_bounds__(256) void k_edgew(
        const float* __restrict__ als, const float* __restrict__ ald,
        const int* __restrict__ off, const int* __restrict__ cnt,
        const int* __restrict__ csr,
        unsigned* __restrict__ ew, float* __restrict__ invden, int n) {
    const int fl = threadIdx.x & 15;
    const int v = blockIdx.x * 16 + (threadIdx.x >> 4);
    if (v >= n) return;
    const int start = off[v], end = start + cnt[v];
    const int pend = off[v + 1];
    const float aldv = ald[v];
    float s = 0.f;
    for (int j = start + fl; j < end; j += 16) {
        int src = __builtin_nontemporal_load(&csr[j]);
        float e = als[src] + aldv;
        e = e > 0.f ? e : 0.2f * e;
        unsigned r = bf16_rne(__expf(e));
        ew[j] = ((unsigned)src << 16) | r;
        s += __uint_as_float(r << 16);
    }
    for (int j = end + fl; j < pend; j += 16) ew[j] = 0;   // pad slots
    #pragma unroll
    for (int d = 1; d < 16; d <<= 1) s += __shfl_xor(s, d);
    if (fl == 0) invden[v] = 1.f / (s + 1e-16f);
}

// ---------------- unified SpMM (bf16 H, 32-feature chunks) ----------------
// Wave = 16 nodes; 4-lane sub owns one node; lane = 8 bf16 feats (16B).
// One gather instr = 16 independent fully-used 64B lines.
// chunk = blockIdx.x % NCH pins each 3.2MB H slice to one XCD's L2.
// PACKOUT=true (layer1): write y1 in Xb-tiled bf16 layout for gemm2.
// PACKOUT=false (layer2): write final f32 out (nt, pure write-stream).
template<int F, bool RELU, bool PACKOUT>
__global__ __launch_bounds__(256) void k_spmm_b(
        const unsigned short* __restrict__ Hb, const unsigned* __restrict__ ew,
        const float* __restrict__ invden, const float* __restrict__ bias,
        const int* __restrict__ off, void* __restrict__ outv, int n) {
    constexpr int NCH = F / 32;
    const int chunk = blockIdx.x % NCH;
    const int v = (blockIdx.x / NCH) * 64 + (threadIdx.x >> 2);
    if (v >= n) return;
    const int q = threadIdx.x & 3;                // 8-feat group 0..3
    const int start = off[v], end = off[v + 1];   // padded: multiple of 4, >= 4
    const unsigned short* __restrict__ Hch = Hb + (size_t)chunk * (size_t)n * 32 + q * 8;

    float a0[8] = {}, a1[8] = {}, a2[8] = {}, a3[8] = {};

    #define GATB(E, A)                                                   \
        {                                                                \
            float w_ = __uint_as_float((E) << 16);                       \
            uint4 h_ = *(const uint4*)&Hch[(size_t)((E) >> 16) * 32];    \
            A[0] += w_ * __uint_as_float(h_.x << 16);                    \
            A[1] += w_ * __uint_as_float(h_.x & 0xffff0000u);            \
            A[2] += w_ * __uint_as_float(h_.y << 16);                    \
            A[3] += w_ * __uint_as_float(h_.y & 0xffff0000u);            \
            A[4] += w_ * __uint_as_float(h_.z << 16);                    \
            A[5] += w_ * __uint_as_float(h_.z & 0xffff0000u);            \
            A[6] += w_ * __uint_as_float(h_.w << 16);                    \
            A[7] += w_ * __uint_as_float(h_.w & 0xffff0000u);            \
        }
    #define GATB4(Q) GATB((Q).x, a0) GATB((Q).y, a1) GATB((Q).z, a2) GATB((Q).w, a3)

    int j = start;
    for (; j + 4 < end; j += 8) {
        uint4 eA = *(const uint4*)&ew[j];
        uint4 eB = *(const uint4*)&ew[j + 4];
        GATB4(eA)
        GATB4(eB)
    }
    if (j < end) {
        uint4 eA = *(const uint4*)&ew[j];
        GATB4(eA)
    }
    #undef GATB4
    #undef GATB

    const float inv = invden[v];
    const float* __restrict__ bp = bias + chunk * 32 + q * 8;
    float s[8];
    #pragma unroll
    for (int i = 0; i < 8; ++i) {
        s[i] = (a0[i] + a1[i] + a2[i] + a3[i]) * inv + bp[i];
        if (RELU) s[i] = fmaxf(s[i], 0.f);
    }

    if (PACKOUT) {
        unsigned short* Xb2 = (unsigned short*)outv;
        const int kg = chunk * 4 + q;
        uint4v p;
        p[0] = pack2(s[0], s[1]); p[1] = pack2(s[2], s[3]);
        p[2] = pack2(s[4], s[5]); p[3] = pack2(s[6], s[7]);
        __builtin_nontemporal_store(p,
            (uint4v*)&Xb2[(size_t)(v >> 4) * 2048 + kg * 128 + (v & 15) * 8]);
    } else {
        float* out = (float*)outv;
        float4v o0, o1;
        o0[0] = s[0]; o0[1] = s[1]; o0[2] = s[2]; o0[3] = s[3];
        o1[0] = s[4]; o1[1] = s[5]; o1[2] = s[6]; o1[3] = s[7];
        float* op = out + (size_t)v * F + chunk * 32 + q * 8;
        __builtin_nontemporal_store(o0, (float4v*)op);
        __builtin_nontemporal_store(o1, (float4v*)(op + 4));
    }
}

// ---------------- launch ----------------

extern "C" void kernel_launch(void* const* d_in, const int* in_sizes, int n_in,
                              void* d_out, int out_size, void* d_ws, size_t ws_size,
                              hipStream_t stream) {
    const float* x     = (const float*)d_in[0];
    const int*   ei    = (const int*)d_in[1];
    const float* W1    = (const float*)d_in[2];
    const float* as1   = (const float*)d_in[3];
    const float* ad1   = (const float*)d_in[4];
    const float* b1    = (const float*)d_in[5];
    const float* W2    = (const float*)d_in[6];
    const float* as2   = (const float*)d_in[7];
    const float* ad2   = (const float*)d_in[8];
    const float* b2    = (const float*)d_in[9];
    float* out = (float*)d_out;

    const int Nn = N_NODES, E = N_EDGES, ET = N_TOT_EDGES;

    // workspace carve-up (256B aligned)
    char* ws = (char*)d_ws;
    size_t o = 0;
    auto carve = [&](size_t bytes) { char* p = ws + o; o = (o + bytes + 255) & ~(size_t)255; return p; };
    int*            off  = (int*)carve((Nn + 1) * sizeof(int));
    int*            cnt  = (int*)carve(Nn * sizeof(int));
    int*            bsum = (int*)carve(256 * sizeof(int));
    unsigned short* rank = (unsigned short*)carve((size_t)E * sizeof(unsigned short));
    int*            csr  = (int*)carve((size_t)ET_PAD * sizeof(int));
    unsigned*       ew   = (unsigned*)carve((size_t)ET_PAD * sizeof(unsigned));
    unsigned short* h1b  = (unsigned short*)carve((size_t)Nn * HID * sizeof(unsigned short));
    unsigned short* h2b  = (unsigned short*)carve((size_t)Nn * OUT_CH * sizeof(unsigned short));
    unsigned short* Xb1  = (unsigned short*)carve((size_t)MPAD * 128 * sizeof(unsigned short));
    unsigned short* Xb2  = (unsigned short*)carve((size_t)MPAD * 128 * sizeof(unsigned short));
    unsigned short* Wl1  = (unsigned short*)carve(16 * 128 * 8 * sizeof(unsigned short));
    unsigned short* Wl2  = (unsigned short*)carve(16 * 64 * 8 * sizeof(unsigned short));
    float*          als  = (float*)carve(Nn * sizeof(float));
    float*          ald  = (float*)carve(Nn * sizeof(float));
    float*          invd = (float*)carve(Nn * sizeof(float));

    const int nbE   = (E + 255) / 256;
    const int nbET  = (ET + 255) / 256;

    // fused conversions + cnt init (independent of edge stream)
    k_cvtAll<<<NBX + 12 + NBN, 256, 0, stream>>>(x, Xb1, W1, Wl1, W2, Wl2, cnt, Nn);

    // CSR build: count captures ranks; fill is atomic-free; no ew memset
    k_count<<<nbE, 256, 0, stream>>>(ei + E, cnt, rank, E);
    k_scan1<<<NBN, 256, 0, stream>>>(cnt, off, bsum, Nn);
    k_scan2<<<1, 256, 0, stream>>>(bsum, NBN);
    k_scan3<<<NBN, 256, 0, stream>>>(off, bsum, Nn);
    k_fill2<<<nbET, 256, 0, stream>>>(ei, off, rank, csr, E, Nn);

    const int nbEW   = (Nn + 15) / 16;
    const int nbN64  = (Nn + 63) / 64;
    const int nbGEMM = MPAD / 64;   // 782

    // layer 1: bf16 H, 4 chunk passes; y1 written in Xb-tiled bf16 layout
    gemm_mfma<HID><<<nbGEMM, 256, 0, stream>>>(
        Xb1, Wl1, as1, ad1, h1b, als, ald, Nn);
    k_edgew<<<nbEW, 256, 0, stream>>>(als, ald, off, cnt, csr, ew, invd, Nn);
    k_spmm_b<HID, true, true><<<nbN64 * (HID / 32), 256, 0, stream>>>(
        h1b, ew, invd, b1, off, Xb2, Nn);

    // layer 2: bf16 H, 2 chunk passes; final f32 out
    gemm_mfma<OUT_CH><<<nbGEMM, 256, 0, stream>>>(
        Xb2, Wl2, as2, ad2, h2b, als, ald, Nn);
    k_edgew<<<nbEW, 256, 0, stream>>>(als, ald, off, cnt, csr, ew, invd, Nn);
    k_spmm_b<OUT_CH, false, false><<<nbN64 * (OUT_CH / 32), 256, 0, stream>>>(
        h2b, ew, invd, b2, off, out, Nn);
}

// Round 18
// 162.743 us; speedup vs baseline: 1.0768x; 1.0141x over previous
//
#include <hip/hip_runtime.h>
#include <hip/hip_bf16.h>

#define N_NODES 50000
#define IN_CH 128
#define HID 128
#define OUT_CH 64
#define N_EDGES 800000
#define N_TOT_EDGES (N_EDGES + N_NODES)         // + self loops
#define ET_PAD (N_TOT_EDGES + 3 * N_NODES)      // worst-case pad-to-4 per node
#define MPAD 50048                              // 782 * 64 (gemm row-block pad)
#define NBX (MPAD / 16)                         // 3128 cvtX blocks
#define NBN ((N_NODES + 255) / 256)             // 196
#define NB_E ((N_EDGES + 255) / 256)            // 3125
#define NB_ET ((N_TOT_EDGES + 255) / 256)       // 3321
#define NB_CVT (NBX + 12)                       // 3140
#define NB_GEMM (MPAD / 64)                     // 782

typedef float float4v __attribute__((ext_vector_type(4)));
typedef unsigned uint4v __attribute__((ext_vector_type(4)));
typedef __attribute__((ext_vector_type(8))) short bf16x8;
typedef __attribute__((ext_vector_type(4))) float f32x4;

__device__ __forceinline__ unsigned bf16_rne(float f) {
    unsigned u = __float_as_uint(f);
    return (u + 0x7fffu + ((u >> 16) & 1u)) >> 16;
}
__device__ __forceinline__ unsigned pack2(float a, float b) {
    return bf16_rne(a) | (bf16_rne(b) << 16);
}

// ---------------- device bodies (shared by merged dispatches) ----------------

// count + RANK capture: rank[i] = old count (1..deg) -> fill is atomic-free.
__device__ __forceinline__ void count_body(int b, int t,
        const int* __restrict__ dst_row, int* __restrict__ cnt,
        unsigned short* __restrict__ rank, int e) {
    int i = b * 256 + t;
    if (i < e) {
        int d = __builtin_nontemporal_load(&dst_row[i]);   // read-once stream
        rank[i] = (unsigned short)atomicAdd(&cnt[d], 1);
    }
}

// f32 -> bf16 tiled conversions (X, W1, W2)
__device__ __forceinline__ void cvt_body(int b, int t,
        const float* __restrict__ X, unsigned short* __restrict__ Xb,
        const float* __restrict__ W1, unsigned short* __restrict__ Wl1,
        const float* __restrict__ W2, unsigned short* __restrict__ Wl2, int M) {
    if (b < NBX) {
        const int kg = t >> 4, rl = t & 15;
        const int row = b * 16 + rl;
        float4 a = make_float4(0.f, 0.f, 0.f, 0.f), c = a;
        if (row < M) {
            a = *(const float4*)&X[(size_t)row * 128 + kg * 8];
            c = *(const float4*)&X[(size_t)row * 128 + kg * 8 + 4];
        }
        uint4 p;
        p.x = pack2(a.x, a.y); p.y = pack2(a.z, a.w);
        p.z = pack2(c.x, c.y); p.w = pack2(c.z, c.w);
        *(uint4*)&Xb[(size_t)b * 2048 + kg * 128 + rl * 8] = p;
        return;
    }
    const float* W; unsigned short* Wl; int N, bb;
    if (b < NBX + 8) { W = W1; Wl = Wl1; N = 128; bb = b - NBX; }
    else             { W = W2; Wl = Wl2; N = 64;  bb = b - NBX - 8; }
    const int tg = bb * 256 + t;
    if (tg >= 16 * N) return;
    const int kg = tg / N, col = tg & (N - 1);
    float v[8];
    #pragma unroll
    for (int j = 0; j < 8; ++j) v[j] = W[(size_t)(kg * 8 + j) * N + col];
    uint4 p;
    p.x = pack2(v[0], v[1]); p.y = pack2(v[2], v[3]);
    p.z = pack2(v[4], v[5]); p.w = pack2(v[6], v[7]);
    *(uint4*)&Wl[(size_t)tg * 8] = p;
}

// atomic-free fill: edge i -> csr[off[dst] + rank[i]]; self-loop v -> slot 0.
__device__ __forceinline__ void fill_body(int b, int t,
        const int* __restrict__ ei, const int* __restrict__ off,
        const unsigned short* __restrict__ rank,
        int* __restrict__ csr, int e, int n) {
    int i = b * 256 + t;
    if (i < e) {
        int src = __builtin_nontemporal_load(&ei[i]);
        int dst = __builtin_nontemporal_load(&ei[e + i]);
        csr[off[dst] + rank[i]] = src;
    } else if (i < e + n) {
        int v = i - e;
        csr[off[v]] = v;
    }
}

// MFMA GEMM body: block = 4 waves; wave = 16 rows x ALL N cols.
// C/D layout (guide-verified m89/m91): col = lane&15, row = (lane>>4)*4 + reg.
// Emits bf16 H in 32-feature chunks; attention dots atomic-free.
template<int N>
__device__ __forceinline__ void gemm_body(int gb, int t,
        const unsigned short* __restrict__ Xb, const unsigned short* __restrict__ Wlg,
        const float* __restrict__ asrc, const float* __restrict__ adst,
        unsigned short* __restrict__ Hb, float* __restrict__ als,
        float* __restrict__ ald, int M, unsigned short* Wl) {
    constexpr int NF = N / 16;
    for (int i = t; i < N * 16; i += 256)
        ((uint4*)Wl)[i] = ((const uint4*)Wlg)[i];
    __syncthreads();

    const int lane = t & 63, w = t >> 6;
    const int rb = gb * 64 + w * 16;
    const int cl = lane & 15, g = lane >> 4;
    const unsigned short* __restrict__ Abase = Xb + (size_t)(rb >> 4) * 2048 + cl * 8;

    f32x4 acc[NF];
    #pragma unroll
    for (int n = 0; n < NF; ++n) acc[n] = (f32x4){0.f, 0.f, 0.f, 0.f};

    #pragma unroll
    for (int s = 0; s < 4; ++s) {
        bf16x8 af = *(const bf16x8*)(Abase + (s * 4 + g) * 128);
        #pragma unroll
        for (int n = 0; n < NF; ++n) {
            bf16x8 bf = *(const bf16x8*)(Wl + ((s * 4 + g) * N + n * 16 + cl) * 8);
            acc[n] = __builtin_amdgcn_mfma_f32_16x16x32_bf16(af, bf, acc[n], 0, 0, 0);
        }
    }

    float asv[NF], adv[NF];
    #pragma unroll
    for (int n = 0; n < NF; ++n) {
        asv[n] = asrc[n * 16 + cl];
        adv[n] = adst[n * 16 + cl];
    }

    #pragma unroll
    for (int r = 0; r < 4; ++r) {
        float ps = 0.f, pd = 0.f;
        #pragma unroll
        for (int n = 0; n < NF; ++n) {
            ps += acc[n][r] * asv[n];
            pd += acc[n][r] * adv[n];
        }
        #pragma unroll
        for (int mask = 1; mask < 16; mask <<= 1) {
            ps += __shfl_xor(ps, mask);
            pd += __shfl_xor(pd, mask);
        }
        const int row = rb + g * 4 + r;
        if (cl == 0 && row < M) { als[row] = ps; ald[row] = pd; }
    }

    #pragma unroll
    for (int r = 0; r < 4; ++r) {
        const int row = rb + g * 4 + r;
        if (row >= M) continue;
        #pragma unroll
        for (int n = 0; n < NF; ++n)
            Hb[(size_t)(n >> 1) * (size_t)M * 32 + (size_t)row * 32
               + (n & 1) * 16 + cl] = (unsigned short)bf16_rne(acc[n][r]);
    }
}

// ---------------- kernels ----------------

__global__ void k_init_cnt(int* cnt, int n) {
    int i = blockIdx.x * 256 + threadIdx.x;
    if (i < n) cnt[i] = 1;   // self-loop reserves slot 0 of each segment
}

// merged dispatch 1: [count || cvtAll] — independent (cnt/rank vs Xb/Wl).
// count blocks FIRST (longer pole: 800K device atomics) so they start early.
__global__ __launch_bounds__(256) void k_par1(
        const int* __restrict__ ei, int* __restrict__ cnt,
        unsigned short* __restrict__ rank,
        const float* __restrict__ X, unsigned short* __restrict__ Xb,
        const float* __restrict__ W1, unsigned short* __restrict__ Wl1,
        const float* __restrict__ W2, unsigned short* __restrict__ Wl2, int M) {
    const int b = blockIdx.x, t = threadIdx.x;
    if (b < NB_E) count_body(b, t, ei + N_EDGES, cnt, rank, N_EDGES);
    else         cvt_body(b - NB_E, t, X, Xb, W1, Wl1, W2, Wl2, M);
}

// inclusive scan of PADDED counts -> off[i+1]; per-block sums to bsum.
__global__ void k_scan1(const int* __restrict__ cnt, int* __restrict__ off,
                        int* __restrict__ bsum, int n) {
    __shared__ int s[256];
    int t = threadIdx.x;
    int i = blockIdx.x * 256 + t;
    int v = (i < n) ? ((cnt[i] + 3) & ~3) : 0;   // pad segments to 4
    s[t] = v;
    __syncthreads();
    for (int d = 1; d < 256; d <<= 1) {
        int x = (t >= d) ? s[t - d] : 0;
        __syncthreads();
        s[t] += x;
        __syncthreads();
    }
    if (i < n) off[i + 1] = s[t];
    if (t == 255) bsum[blockIdx.x] = s[255];
}

__global__ void k_scan2(int* __restrict__ bsum, int nb) {  // single block, nb <= 256
    __shared__ int s[256];
    int t = threadIdx.x;
    int v = (t < nb) ? bsum[t] : 0;
    s[t] = v;
    __syncthreads();
    for (int d = 1; d < 256; d <<= 1) {
        int x = (t >= d) ? s[t - d] : 0;
        __syncthreads();
        s[t] += x;
        __syncthreads();
    }
    if (t < nb) bsum[t] = s[t] - v;  // exclusive prefix
}

__global__ void k_scan3(int* __restrict__ off, const int* __restrict__ bsum, int n) {
    int i = blockIdx.x * 256 + threadIdx.x;
    if (i < n) off[i + 1] += bsum[blockIdx.x];
    if (i == 0) off[0] = 0;
}

// merged dispatch 2: [fill2 || gemm1] — independent (csr vs h1b/als/ald).
// fill blocks FIRST (longer pole: 850K-entry scatter). Static 32KB LDS caps
// everyone at 5 blocks/CU; fill still gets ~20 waves/CU for latency hiding.
__global__ __launch_bounds__(256) void k_par2(
        const int* __restrict__ ei, const int* __restrict__ off,
        const unsigned short* __restrict__ rank, int* __restrict__ csr,
        const unsigned short* __restrict__ Xb, const unsigned short* __restrict__ Wlg,
        const float* __restrict__ asrc, const float* __restrict__ adst,
        unsigned short* __restrict__ Hb, float* __restrict__ als,
        float* __restrict__ ald, int M) {
    __shared__ unsigned short Wl[16 * 128 * 8];   // 32 KB (gemm role only)
    const int b = blockIdx.x, t = threadIdx.x;
    if (b < NB_ET) fill_body(b, t, ei, off, rank, csr, N_EDGES, N_NODES);
    else gemm_body<HID>(b - NB_ET, t, Xb, Wlg, asrc, adst, Hb, als, ald, M, Wl);
}

// standalone layer-2 GEMM
__global__ __launch_bounds__(256) void gemm_mfma64(
        const unsigned short* __restrict__ Xb, const unsigned short* __restrict__ Wlg,
        const float* __restrict__ asrc, const float* __restrict__ adst,
        unsigned short* __restrict__ Hb, float* __restrict__ als,
        float* __restrict__ ald, int M) {
    __shared__ unsigned short Wl[16 * 64 * 8];    // 16 KB
    gemm_body<OUT_CH>(blockIdx.x, threadIdx.x, Xb, Wlg, asrc, adst, Hb, als, ald, M, Wl);
}

// ---------------- edge weights: packed u32 = (src<<16) | bf16(exp(leaky(e))) ----
// PADZ: zero the <=3 pad slots per node (layer 1 only; pads persist after).
template<bool PADZ>
__global__ __launch_bounds__(256) void k_edgew(
        const float* __restrict__ als, const float* __restrict__ ald,
        const int* __restrict__ off, const int* __restrict__ cnt,
        const int* __restrict__ csr,
        unsigned* __restrict__ ew, float* __restrict__ invden, int n) {
    const int fl = threadIdx.x & 15;
    const int v = blockIdx.x * 16 + (threadIdx.x >> 4);
    if (v >= n) return;
    const int start = off[v], end = start + cnt[v];
    const float aldv = ald[v];
    float s = 0.f;
    for (int j = start + fl; j < end; j += 16) {
        int src = __builtin_nontemporal_load(&csr[j]);
        float e = als[src] + aldv;
        e = e > 0.f ? e : 0.2f * e;
        unsigned r = bf16_rne(__expf(e));
        ew[j] = ((unsigned)src << 16) | r;
        s += __uint_as_float(r << 16);
    }
    if (PADZ) {
        const int pend = off[v + 1];
        for (int j = end + fl; j < pend; j += 16) ew[j] = 0;   // pad slots
    }
    #pragma unroll
    for (int d = 1; d < 16; d <<= 1) s += __shfl_xor(s, d);
    if (fl == 0) invden[v] = 1.f / (s + 1e-16f);
}

// ---------------- unified SpMM (bf16 H, 32-feature chunks) ----------------
// Wave = 16 nodes; 4-lane sub owns one node; lane = 8 bf16 feats (16B).
// One gather instr = 16 independent fully-used 64B lines.
// chunk = blockIdx.x % NCH pins each 3.2MB H slice to one XCD's L2.
template<int F, bool RELU, bool PACKOUT>
__global__ __launch_bounds__(256) void k_spmm_b(
        const unsigned short* __restrict__ Hb, const unsigned* __restrict__ ew,
        const float* __restrict__ invden, const float* __restrict__ bias,
        const int* __restrict__ off, void* __restrict__ outv, int n) {
    constexpr int NCH = F / 32;
    const int chunk = blockIdx.x % NCH;
    const int v = (blockIdx.x / NCH) * 64 + (threadIdx.x >> 2);
    if (v >= n) return;
    const int q = threadIdx.x & 3;                // 8-feat group 0..3
    const int start = off[v], end = off[v + 1];   // padded: multiple of 4, >= 4
    const unsigned short* __restrict__ Hch = Hb + (size_t)chunk * (size_t)n * 32 + q * 8;

    float a0[8] = {}, a1[8] = {}, a2[8] = {}, a3[8] = {};

    #define GATB(E, A)                                                   \
        {                                                                \
            float w_ = __uint_as_float((E) << 16);                       \
            uint4 h_ = *(const uint4*)&Hch[(size_t)((E) >> 16) * 32];    \
            A[0] += w_ * __uint_as_float(h_.x << 16);                    \
            A[1] += w_ * __uint_as_float(h_.x & 0xffff0000u);            \
            A[2] += w_ * __uint_as_float(h_.y << 16);                    \
            A[3] += w_ * __uint_as_float(h_.y & 0xffff0000u);            \
            A[4] += w_ * __uint_as_float(h_.z << 16);                    \
            A[5] += w_ * __uint_as_float(h_.z & 0xffff0000u);            \
            A[6] += w_ * __uint_as_float(h_.w << 16);                    \
            A[7] += w_ * __uint_as_float(h_.w & 0xffff0000u);            \
        }
    #define GATB4(Q) GATB((Q).x, a0) GATB((Q).y, a1) GATB((Q).z, a2) GATB((Q).w, a3)

    int j = start;
    for (; j + 4 < end; j += 8) {
        uint4 eA = *(const uint4*)&ew[j];
        uint4 eB = *(const uint4*)&ew[j + 4];
        GATB4(eA)
        GATB4(eB)
    }
    if (j < end) {
        uint4 eA = *(const uint4*)&ew[j];
        GATB4(eA)
    }
    #undef GATB4
    #undef GATB

    const float inv = invden[v];
    const float* __restrict__ bp = bias + chunk * 32 + q * 8;
    float s[8];
    #pragma unroll
    for (int i = 0; i < 8; ++i) {
        s[i] = (a0[i] + a1[i] + a2[i] + a3[i]) * inv + bp[i];
        if (RELU) s[i] = fmaxf(s[i], 0.f);
    }

    if (PACKOUT) {
        unsigned short* Xb2 = (unsigned short*)outv;
        const int kg = chunk * 4 + q;
        uint4v p;
        p[0] = pack2(s[0], s[1]); p[1] = pack2(s[2], s[3]);
        p[2] = pack2(s[4], s[5]); p[3] = pack2(s[6], s[7]);
        __builtin_nontemporal_store(p,
            (uint4v*)&Xb2[(size_t)(v >> 4) * 2048 + kg * 128 + (v & 15) * 8]);
    } else {
        float* out = (float*)outv;
        float4v o0, o1;
        o0[0] = s[0]; o0[1] = s[1]; o0[2] = s[2]; o0[3] = s[3];
        o1[0] = s[4]; o1[1] = s[5]; o1[2] = s[6]; o1[3] = s[7];
        float* op = out + (size_t)v * F + chunk * 32 + q * 8;
        __builtin_nontemporal_store(o0, (float4v*)op);
        __builtin_nontemporal_store(o1, (float4v*)(op + 4));
    }
}

// ---------------- launch ----------------

extern "C" void kernel_launch(void* const* d_in, const int* in_sizes, int n_in,
                              void* d_out, int out_size, void* d_ws, size_t ws_size,
                              hipStream_t stream) {
    const float* x     = (const float*)d_in[0];
    const int*   ei    = (const int*)d_in[1];
    const float* W1    = (const float*)d_in[2];
    const float* as1   = (const float*)d_in[3];
    const float* ad1   = (const float*)d_in[4];
    const float* b1    = (const float*)d_in[5];
    const float* W2    = (const float*)d_in[6];
    const float* as2   = (const float*)d_in[7];
    const float* ad2   = (const float*)d_in[8];
    const float* b2    = (const float*)d_in[9];
    float* out = (float*)d_out;

    const int Nn = N_NODES;

    // workspace carve-up (256B aligned)
    char* ws = (char*)d_ws;
    size_t o = 0;
    auto carve = [&](size_t bytes) { char* p = ws + o; o = (o + bytes + 255) & ~(size_t)255; return p; };
    int*            off  = (int*)carve((Nn + 1) * sizeof(int));
    int*            cnt  = (int*)carve(Nn * sizeof(int));
    int*            bsum = (int*)carve(256 * sizeof(int));
    unsigned short* rank = (unsigned short*)carve((size_t)N_EDGES * sizeof(unsigned short));
    int*            csr  = (int*)carve((size_t)ET_PAD * sizeof(int));
    unsigned*       ew   = (unsigned*)carve((size_t)ET_PAD * sizeof(unsigned));
    unsigned short* h1b  = (unsigned short*)carve((size_t)Nn * HID * sizeof(unsigned short));
    unsigned short* h2b  = (unsigned short*)carve((size_t)Nn * OUT_CH * sizeof(unsigned short));
    unsigned short* Xb1  = (unsigned short*)carve((size_t)MPAD * 128 * sizeof(unsigned short));
    unsigned short* Xb2  = (unsigned short*)carve((size_t)MPAD * 128 * sizeof(unsigned short));
    unsigned short* Wl1  = (unsigned short*)carve(16 * 128 * 8 * sizeof(unsigned short));
    unsigned short* Wl2  = (unsigned short*)carve(16 * 64 * 8 * sizeof(unsigned short));
    float*          als  = (float*)carve(Nn * sizeof(float));
    float*          ald  = (float*)carve(Nn * sizeof(float));
    float*          invd = (float*)carve(Nn * sizeof(float));

    // D1: cnt init (must precede count atomics)
    k_init_cnt<<<NBN, 256, 0, stream>>>(cnt, Nn);

    // D2: [count || cvtAll]
    k_par1<<<NB_E + NB_CVT, 256, 0, stream>>>(
        ei, cnt, rank, x, Xb1, W1, Wl1, W2, Wl2, Nn);

    // D3-5: scans (padded-to-4 segments)
    k_scan1<<<NBN, 256, 0, stream>>>(cnt, off, bsum, Nn);
    k_scan2<<<1, 256, 0, stream>>>(bsum, NBN);
    k_scan3<<<NBN, 256, 0, stream>>>(off, bsum, Nn);

    // D6: [fill2 || gemm1]
    k_par2<<<NB_ET + NB_GEMM, 256, 0, stream>>>(
        ei, off, rank, csr, Xb1, Wl1, as1, ad1, h1b, als, ald, Nn);

    const int nbEW  = (Nn + 15) / 16;
    const int nbN64 = (Nn + 63) / 64;

    // D7-8: layer-1 edge weights + SpMM (y1 written in Xb-tiled bf16 layout)
    k_edgew<true><<<nbEW, 256, 0, stream>>>(als, ald, off, cnt, csr, ew, invd, Nn);
    k_spmm_b<HID, true, true><<<nbN64 * (HID / 32), 256, 0, stream>>>(
        h1b, ew, invd, b1, off, Xb2, Nn);

    // D9-11: layer 2
    gemm_mfma64<<<NB_GEMM, 256, 0, stream>>>(
        Xb2, Wl2, as2, ad2, h2b, als, ald, Nn);
    k_edgew<false><<<nbEW, 256, 0, stream>>>(als, ald, off, cnt, csr, ew, invd, Nn);
    k_spmm_b<OUT_CH, false, false><<<nbN64 * (OUT_CH / 32), 256, 0, stream>>>(
        h2b, ew, invd, b2, off, out, Nn);
}